// Round 3
// baseline (516.208 us; speedup 1.0000x reference)
//
#include <hip/hip_runtime.h>
#include <float.h>

// Viterbi decode: B=1024, T=1024, K=48.
// fwd (R2): 2 waves/block. Wave w owns nexts 24w..24w+23; within a wave,
//   lane=(next_local, prev_half): each 32-lane half reduces over 24 prevs
//   (6x ds_read_b128 same-address broadcast + 24 adds + max3 tree), halves
//   combined with one __shfl_xor(32). Double-buffered fvbuf[2][48], one
//   __syncthreads per step. Bit-exact vs 48-wide max (fp32 max is
//   order-independent) -> mx / scores / bwd equality vote unchanged.
//   tr half-rows pinned in regs, feat rows double-buffered in blocks of 8.
// bwd: equality backtrack. mx/feat rows bulk-loaded in blocks of 8 with
//   ping-pong buffers (single waitcnt per block, not per step). Vote:
//   s = F + tr_row == mx_j[tag] -> ballot -> ctz (first index == np.argmax).
// FALLBACK (ws < 201MB): R1 structure.

#define BB 1024
#define TT 1024
#define KK 48
#define CC 16
#define LL 64
#define NEGV -10000.0f

__device__ __forceinline__ float rdlane(float v, int l) {
  return __int_as_float(__builtin_amdgcn_readlane(__float_as_int(v), l));
}
__device__ __forceinline__ float max3f(float a, float b, float c) {
  return fmaxf(fmaxf(a, b), c);
}

// ---------------- main path ----------------

// One Viterbi step for the 2-wave split. Reads fv from fvbuf[CUR_],
// writes fv_{t+1} to fvbuf[CUR_^1], one barrier per step.
#define FSTEP2(T_, FEAT_, CUR_)                                            \
  {                                                                        \
    float fvr[24];                                                         \
    _Pragma("unroll") for (int j = 0; j < 6; ++j) {                        \
      float4 v4 = *(const float4*)(&fvbuf[(CUR_)][hbase + 4 * j]);         \
      fvr[4 * j + 0] = v4.x; fvr[4 * j + 1] = v4.y;                        \
      fvr[4 * j + 2] = v4.z; fvr[4 * j + 3] = v4.w;                        \
    }                                                                      \
    float s_[24];                                                          \
    _Pragma("unroll") for (int p = 0; p < 24; ++p) {                       \
      s_[p] = fvr[p] + tr[p];                                              \
    }                                                                      \
    float part[8];                                                         \
    _Pragma("unroll") for (int g = 0; g < 8; ++g) {                        \
      part[g] = max3f(s_[3 * g], s_[3 * g + 1], s_[3 * g + 2]);            \
    }                                                                      \
    float q0 = max3f(part[0], part[1], part[2]);                           \
    float q1 = max3f(part[3], part[4], part[5]);                           \
    float q2 = fmaxf(part[6], part[7]);                                    \
    float pm = max3f(q0, q1, q2);                                          \
    float om = __shfl_xor(pm, 32);                                         \
    float m_ = fmaxf(pm, om);                                              \
    if (stLane) mp[(size_t)(T_)*KK] = m_;                                  \
    fv = m_ + (FEAT_);                                                     \
    if (wrLane) fvbuf[(CUR_) ^ 1][nxt] = fv;                               \
    __syncthreads();                                                       \
  }

__global__ __launch_bounds__(128, 1) void viterbi_fwd_mx(
    const float* __restrict__ feats, const float* __restrict__ trans,
    float* __restrict__ scores, float* __restrict__ mx,
    int* __restrict__ bestArr) {
  __shared__ __align__(16) float fvbuf[2][KK];
  __shared__ float sc[2];
  __shared__ int si[2];
  const int tid = threadIdx.x;
  const int w = tid >> 6;       // wave id: owns nexts 24w..24w+23
  const int lane = tid & 63;
  const int li = lane & 31;     // next_local (0..23 active)
  const int h = lane >> 5;      // prev half: prevs [24h, 24h+24)
  const int lic = (li < 24) ? li : 23;
  const int nxt = 24 * w + lic; // this lane's next tag (clamped)
  const int b = blockIdx.x;
  const bool wrLane = (h == 0) && (li < 24);  // writes fv to LDS
  const bool stLane = (h == 1) && (li < 24);  // stores mx row half
  const int hbase = 24 * h;

  // tr[j] = trans[nxt][24h + j] : this lane's half of the transition row
  float tr[24];
#pragma unroll
  for (int j = 0; j < 6; ++j) {
    float4 t4 = *(const float4*)(trans + nxt * KK + 24 * h + 4 * j);
    tr[4 * j + 0] = t4.x; tr[4 * j + 1] = t4.y;
    tr[4 * j + 2] = t4.z; tr[4 * j + 3] = t4.w;
  }
  // pin: block rematerialization / spilling of the transition half-row
#pragma unroll
  for (int j = 0; j < 24; ++j) asm volatile("" : "+v"(tr[j]));
  const float tstop = trans[(KK - 1) * KK + nxt];

  const float* fp = feats + (size_t)b * TT * KK + nxt;
  float* mp = mx + (size_t)b * TT * KK + nxt;

  if (tid < KK) fvbuf[0][tid] = (tid == 46) ? 0.0f : NEGV;  // F_0
  __syncthreads();

  float fv = NEGV;

  float fA[8], fB[8];
#pragma unroll
  for (int k = 0; k < 8; ++k) fA[k] = fp[(size_t)k * KK];

  for (int t0 = 0; t0 < TT; t0 += 16) {
    // bulk prefetch rows t0+8..t0+15 into fB
#pragma unroll
    for (int k = 0; k < 8; ++k)
      fB[k] = fp[(size_t)((t0 + 8 + k) & (TT - 1)) * KK];
#pragma unroll
    for (int u = 0; u < 8; ++u) FSTEP2(t0 + u, fA[u], (u & 1));
    // bulk prefetch rows t0+16..t0+23 into fA
#pragma unroll
    for (int k = 0; k < 8; ++k)
      fA[k] = fp[(size_t)((t0 + 16 + k) & (TT - 1)) * KK];
#pragma unroll
    for (int u = 0; u < 8; ++u) FSTEP2(t0 + 8 + u, fB[u], (u & 1));
  }

  // final: v = fv + trans[STOP][next], argmax over 48 nexts (tie -> lowest)
  float v = wrLane ? (fv + tstop) : -FLT_MAX;
  int idx = nxt;
#pragma unroll
  for (int off = 32; off >= 1; off >>= 1) {
    float ov = __shfl_xor(v, off);
    int oi = __shfl_xor(idx, off);
    bool take = (ov > v) || (ov == v && oi < idx);
    v = take ? ov : v;
    idx = take ? oi : idx;
  }
  if (lane == 0) { sc[w] = v; si[w] = idx; }
  __syncthreads();
  if (tid == 0) {
    float v0 = sc[0], v1 = sc[1];
    bool take = v1 > v0;  // tie -> wave0 (lower indices)
    scores[b] = take ? v1 : v0;
    bestArr[b] = take ? si[1] : si[0];
  }
}

__global__ __launch_bounds__(64, 1) void viterbi_bwd_mx(
    const float* __restrict__ feats, const float* __restrict__ trans,
    const float* __restrict__ mx, const int* __restrict__ bestArr,
    float* __restrict__ path) {
  __shared__ float tl[KK * KK];
  const int lane = threadIdx.x;
  const int b = blockIdx.x;
  const int rl = (lane < KK) ? lane : (KK - 1);
  for (int i = lane; i < KK * KK; i += 64) tl[i] = trans[i];
  __syncthreads();

  const float* fp = feats + (size_t)b * TT * KK + rl;
  const float* mp = mx + (size_t)b * TT * KK + rl;
  int tag = bestArr[b];  // wave-uniform

  float topA = mp[(size_t)(TT - 1) * KK];  // mx_{T-1}
  float MA[8], FE[8], MB[8], FB2[8];
  // block jb=T-1 needs mx/feat rows jb-1-u (u=0..7)
#pragma unroll
  for (int u = 0; u < 8; ++u) {
    MA[u] = mp[(size_t)(TT - 2 - u) * KK];
    FE[u] = fp[(size_t)(TT - 2 - u) * KK];
  }

  int myv = 0;  // lane (j&63) holds path[j]
  for (int jb = TT - 1; jb >= 15; jb -= 16) {
    // bulk load block jb-8 (rows jb-9-u), clamped
#pragma unroll
    for (int u = 0; u < 8; ++u) {
      int r = jb - 9 - u; int rc = r < 0 ? 0 : r;
      MB[u] = mp[(size_t)rc * KK];
      FB2[u] = fp[(size_t)rc * KK];
    }
    // process block jb with topA / MA / FE
#pragma unroll
    for (int u = 0; u < 8; ++u) {
      const int j = jb - u;
      if (lane == (j & 63)) myv = tag;
      if ((j & 63) == 0) path[(size_t)b * TT + j + lane] = (float)myv;
      float Tg = (u == 0) ? topA : MA[u - 1];
      float target = rdlane(Tg, tag);            // mx_j[tag]
      float s = (MA[u] + FE[u]) + tl[tag * KK + rl];
      unsigned long long bal = __ballot(s == target);  // lanes>=48 mirror 47
      tag = (int)__builtin_ctzll(bal);           // first p (np.argmax tie)
    }
    float topB = MA[7];  // mx_{jb-8}
    // bulk load block jb-16 (rows jb-17-u), clamped
#pragma unroll
    for (int u = 0; u < 8; ++u) {
      int r = jb - 17 - u; int rc = r < 0 ? 0 : r;
      MA[u] = mp[(size_t)rc * KK];
      FE[u] = fp[(size_t)rc * KK];
    }
    // process block jb-8 with topB / MB / FB2
#pragma unroll
    for (int u = 0; u < 8; ++u) {
      const int j = jb - 8 - u;
      if (lane == (j & 63)) myv = tag;
      if ((j & 63) == 0) path[(size_t)b * TT + j + lane] = (float)myv;
      float Tg = (u == 0) ? topB : MB[u - 1];
      float target = rdlane(Tg, tag);
      float s = (MB[u] + FB2[u]) + tl[tag * KK + rl];
      unsigned long long bal = __ballot(s == target);
      tag = (int)__builtin_ctzll(bal);  // garbage after j==0 vote: unused
    }
    topA = MB[7];
  }
}

// ---------------- fallback path (R1) ----------------

__global__ __launch_bounds__(64, 1) void viterbi_fwd_f(
    const float* __restrict__ feats, const float* __restrict__ trans,
    float* __restrict__ scores, unsigned char* __restrict__ bptr,
    int* __restrict__ bestArr) {
  __shared__ __align__(16) float fvbuf[64];
  const int lane = threadIdx.x;
  const int b = blockIdx.x;
  const int rl = (lane < KK) ? lane : (KK - 1);

  float tr[KK];
#pragma unroll
  for (int j = 0; j < 12; ++j) {
    float4 t4 = *(const float4*)(trans + rl * KK + 4 * j);
    tr[4 * j + 0] = t4.x; tr[4 * j + 1] = t4.y;
    tr[4 * j + 2] = t4.z; tr[4 * j + 3] = t4.w;
  }
  const float tstop = trans[(KK - 1) * KK + rl];

  if (lane < KK) fvbuf[lane] = (lane == 46) ? 0.0f : NEGV;
  __builtin_amdgcn_wave_barrier();

  const float* fp = feats + (size_t)b * TT * KK + rl;
  unsigned char* bp = bptr + (size_t)b * TT * KK + lane;

  float fbuf[4];
#pragma unroll
  for (int k = 0; k < 4; ++k) fbuf[k] = fp[(size_t)k * KK];

  float fv = NEGV;
  for (int t0 = 0; t0 < TT; t0 += 4) {
#pragma unroll
    for (int u = 0; u < 4; ++u) {
      const int t = t0 + u;
      float fvr[KK];
#pragma unroll
      for (int j = 0; j < 12; ++j) {
        float4 v4 = *(const float4*)(&fvbuf[4 * j]);
        fvr[4 * j + 0] = v4.x; fvr[4 * j + 1] = v4.y;
        fvr[4 * j + 2] = v4.z; fvr[4 * j + 3] = v4.w;
      }
      __builtin_amdgcn_wave_barrier();

      float bs0 = fvr[0] + tr[0], bs1 = fvr[12] + tr[12];
      float bs2 = fvr[24] + tr[24], bs3 = fvr[36] + tr[36];
      int bi0 = 0, bi1 = 12, bi2 = 24, bi3 = 36;
#pragma unroll
      for (int p = 1; p < 12; ++p) {
        float s0 = fvr[p] + tr[p];
        float s1 = fvr[12 + p] + tr[12 + p];
        float s2 = fvr[24 + p] + tr[24 + p];
        float s3 = fvr[36 + p] + tr[36 + p];
        if (s0 > bs0) { bs0 = s0; bi0 = p; }
        if (s1 > bs1) { bs1 = s1; bi1 = 12 + p; }
        if (s2 > bs2) { bs2 = s2; bi2 = 24 + p; }
        if (s3 > bs3) { bs3 = s3; bi3 = 36 + p; }
      }
      bool c1 = bs1 > bs0;
      float m01 = c1 ? bs1 : bs0; int i01 = c1 ? bi1 : bi0;
      bool c3 = bs3 > bs2;
      float m23 = c3 ? bs3 : bs2; int i23 = c3 ? bi3 : bi2;
      bool cf = m23 > m01;
      float m = cf ? m23 : m01; int bpi = cf ? i23 : i01;

      float nfv = m + fbuf[u];
      int tpre = t + 4; if (tpre >= TT) tpre = 0;
      fbuf[u] = fp[(size_t)tpre * KK];

      if (lane < KK) {
        bp[(size_t)t * KK] = (unsigned char)bpi;
        fvbuf[lane] = nfv;
        fv = nfv;
      }
      __builtin_amdgcn_wave_barrier();
    }
  }

  float v = (lane < KK) ? (fv + tstop) : -FLT_MAX;
  int idx = lane;
#pragma unroll
  for (int off = 32; off >= 1; off >>= 1) {
    float ov = __shfl_xor(v, off);
    int oi = __shfl_xor(idx, off);
    bool take = (ov > v) || (ov == v && oi < idx);
    v = take ? ov : v;
    idx = take ? oi : idx;
  }
  if (lane == 0) { scores[b] = v; bestArr[b] = idx; }
}

__global__ __launch_bounds__(256) void bwd_map(
    const unsigned char* __restrict__ bptr, unsigned char* __restrict__ cmap) {
  const int lane = threadIdx.x & 63;
  const int wg = blockIdx.x * 4 + (threadIdx.x >> 6);
  const int b = wg >> 4;
  const int c = wg & (CC - 1);
  const int rl = (lane < KK) ? lane : (KK - 1);
  const unsigned char* bp = bptr + ((size_t)b * TT + (size_t)c * LL) * KK + rl;

  int x = rl;
  const int CH = 16;
  int cur[CH], nxt[CH];
#pragma unroll
  for (int j = 0; j < CH; ++j) cur[j] = bp[(size_t)(LL - CH + j) * KK];
  for (int tb = LL - CH; tb >= 0; tb -= CH) {
    if (tb >= CH) {
#pragma unroll
      for (int j = 0; j < CH; ++j) nxt[j] = bp[(size_t)(tb - CH + j) * KK];
    }
#pragma unroll
    for (int j = CH - 1; j >= 0; --j) x = __shfl(cur[j], x);
    if (tb >= CH) {
#pragma unroll
      for (int j = 0; j < CH; ++j) cur[j] = nxt[j];
    }
  }
  if (lane < KK) cmap[(size_t)wg * KK + lane] = (unsigned char)x;
}

__global__ __launch_bounds__(256) void bwd_entry(
    const unsigned char* __restrict__ cmap, const int* __restrict__ bestArr,
    int* __restrict__ entry) {
  const int lane = threadIdx.x & 63;
  const int b = blockIdx.x * 4 + (threadIdx.x >> 6);
  const int rl = (lane < KK) ? lane : (KK - 1);

  int rows[CC];
#pragma unroll
  for (int c = 0; c < CC; ++c) rows[c] = cmap[((size_t)b * CC + c) * KK + rl];

  int tag = bestArr[b];
  int ev = 0;
#pragma unroll
  for (int c = CC - 1; c >= 0; --c) {
    if (lane == c) ev = tag;
    tag = __shfl(rows[c], tag);
  }
  if (lane < CC) entry[b * CC + lane] = ev;
}

__global__ __launch_bounds__(256) void bwd_emit(
    const unsigned char* __restrict__ bptr, const int* __restrict__ entry,
    float* __restrict__ path) {
  const int lane = threadIdx.x & 63;
  const int wg = blockIdx.x * 4 + (threadIdx.x >> 6);
  const int b = wg >> 4;
  const int c = wg & (CC - 1);
  const int rl = (lane < KK) ? lane : (KK - 1);
  const unsigned char* bp = bptr + ((size_t)b * TT + (size_t)c * LL) * KK + rl;

  int x = entry[b * CC + c];
  int myv = 0;
  const int CH = 16;
  int cur[CH], nxt[CH];
#pragma unroll
  for (int j = 0; j < CH; ++j) cur[j] = bp[(size_t)(LL - CH + j) * KK];
  for (int tb = LL - CH; tb >= 0; tb -= CH) {
    if (tb >= CH) {
#pragma unroll
      for (int j = 0; j < CH; ++j) nxt[j] = bp[(size_t)(tb - CH + j) * KK];
    }
#pragma unroll
    for (int j = CH - 1; j >= 0; --j) {
      if (lane == tb + j) myv = x;
      x = __shfl(cur[j], x);
    }
    if (tb >= CH) {
#pragma unroll
      for (int j = 0; j < CH; ++j) cur[j] = nxt[j];
    }
  }
  path[(size_t)b * TT + (size_t)c * LL + lane] = (float)myv;
}

extern "C" void kernel_launch(void* const* d_in, const int* in_sizes, int n_in,
                              void* d_out, int out_size, void* d_ws,
                              size_t ws_size, hipStream_t stream) {
  const float* feats = (const float*)d_in[0];
  const float* trans = (const float*)d_in[1];
  float* out = (float*)d_out;  // [0,1024): scores; then paths [B*T]

  const size_t MX_BYTES = (size_t)BB * TT * KK * sizeof(float);  // 201.3 MB
  if (ws_size >= MX_BYTES + 4096) {
    float* mx = (float*)d_ws;
    int* bestArr = (int*)((char*)d_ws + MX_BYTES);
    viterbi_fwd_mx<<<dim3(BB), dim3(128), 0, stream>>>(feats, trans, out, mx,
                                                       bestArr);
    viterbi_bwd_mx<<<dim3(BB), dim3(64), 0, stream>>>(feats, trans, mx,
                                                      bestArr, out + BB);
  } else {
    unsigned char* bptr = (unsigned char*)d_ws;
    char* p = (char*)d_ws + (size_t)BB * TT * KK;
    int* bestArr = (int*)p;
    p += BB * sizeof(int);
    unsigned char* cmap = (unsigned char*)p;
    p += (size_t)BB * CC * KK;
    int* entry = (int*)p;

    viterbi_fwd_f<<<dim3(BB), dim3(64), 0, stream>>>(feats, trans, out, bptr,
                                                     bestArr);
    bwd_map<<<dim3(BB * CC / 4), dim3(256), 0, stream>>>(bptr, cmap);
    bwd_entry<<<dim3(BB / 4), dim3(256), 0, stream>>>(cmap, bestArr, entry);
    bwd_emit<<<dim3(BB * CC / 4), dim3(256), 0, stream>>>(bptr, entry,
                                                          out + BB);
  }
}

// Round 4
// 489.977 us; speedup vs baseline: 1.0535x; 1.0535x over previous
//
#include <hip/hip_runtime.h>
#include <float.h>

// Viterbi decode: B=1024, T=1024, K=48.
// fwd (R4): single wave/block (R1 structure). fv broadcast via LDS
//   same-address float4 reads (12x ds_read_b128 hardware broadcast).
//   NEW: entire t-loop exec-masked to lanes 0..47 -> idle lanes no longer
//   issue the broadcast reads, cutting LDS return traffic 64/48 -> 48/48
//   (DS-return per CU is the measured bottleneck: R1 518 cyc/step vs 384
//   model; R2's 2-wave split kept traffic invariant and regressed).
//   tr pinned in regs, feat rows double-buffered in blocks of 8. Stores
//   pre-feat max row mx_t (exact fp32).
// bwd: UNCHANGED from R1 (equality backtrack, ping-pong bulk loads).
// FALLBACK (ws < 201MB): R1 structure.

#define BB 1024
#define TT 1024
#define KK 48
#define CC 16
#define LL 64
#define NEGV -10000.0f

__device__ __forceinline__ float rdlane(float v, int l) {
  return __int_as_float(__builtin_amdgcn_readlane(__float_as_int(v), l));
}
__device__ __forceinline__ float max3f(float a, float b, float c) {
  return fmaxf(fmaxf(a, b), c);
}

// ---------------- main path ----------------

// LDS-broadcast step: fvbuf holds fv_t at entry; 12x float4 same-address
// reads broadcast all 48 values to every (active) lane. Write-back of
// fv_{t+1} at the end; same-wave DS pipe ordering makes the next step's
// reads see it without an explicit waitcnt.
#define FSTEP(T_, FEAT_)                                                   \
  {                                                                        \
    float fvr[KK];                                                         \
    _Pragma("unroll") for (int j = 0; j < 12; ++j) {                       \
      float4 v4 = *(const float4*)(&fvbuf[4 * j]);                         \
      fvr[4 * j + 0] = v4.x; fvr[4 * j + 1] = v4.y;                        \
      fvr[4 * j + 2] = v4.z; fvr[4 * j + 3] = v4.w;                        \
    }                                                                      \
    float s_[KK];                                                          \
    _Pragma("unroll") for (int p = 0; p < KK; ++p) {                       \
      s_[p] = fvr[p] + tr[p];                                              \
    }                                                                      \
    float part[16];                                                        \
    _Pragma("unroll") for (int g = 0; g < 16; ++g) {                       \
      part[g] = max3f(s_[3 * g], s_[3 * g + 1], s_[3 * g + 2]);            \
    }                                                                      \
    float q0 = max3f(part[0], part[1], part[2]);                           \
    float q1 = max3f(part[3], part[4], part[5]);                           \
    float q2 = max3f(part[6], part[7], part[8]);                           \
    float q3 = max3f(part[9], part[10], part[11]);                         \
    float q4 = max3f(part[12], part[13], part[14]);                        \
    float m_ = fmaxf(max3f(q0, q1, q2), max3f(q3, q4, part[15]));          \
    mp[(size_t)(T_)*KK] = m_;                                              \
    fv = m_ + (FEAT_);                                                     \
    __builtin_amdgcn_wave_barrier();                                       \
    fvbuf[lane] = fv;                                                      \
    __builtin_amdgcn_wave_barrier();                                       \
  }

__global__ __launch_bounds__(64, 1) void viterbi_fwd_mx(
    const float* __restrict__ feats, const float* __restrict__ trans,
    float* __restrict__ scores, float* __restrict__ mx,
    int* __restrict__ bestArr) {
  __shared__ __align__(16) float fvbuf[64];
  const int lane = threadIdx.x;
  const int b = blockIdx.x;
  const int rl = (lane < KK) ? lane : (KK - 1);

  float tr[KK];
#pragma unroll
  for (int j = 0; j < 12; ++j) {
    float4 t4 = *(const float4*)(trans + rl * KK + 4 * j);
    tr[4 * j + 0] = t4.x; tr[4 * j + 1] = t4.y;
    tr[4 * j + 2] = t4.z; tr[4 * j + 3] = t4.w;
  }
  // pin: block rematerialization / spilling-to-memory of the transition row
#pragma unroll
  for (int j = 0; j < KK; ++j) asm volatile("" : "+v"(tr[j]));
  const float tstop = trans[(KK - 1) * KK + rl];

  const float* fp = feats + (size_t)b * TT * KK + rl;
  float* mp = mx + (size_t)b * TT * KK + rl;

  float fv = (lane == 46) ? 0.0f : NEGV;  // F_0
  fvbuf[lane] = fv;                       // seed broadcast buffer
  __builtin_amdgcn_wave_barrier();

  // Exec-mask the whole recurrence to the 48 live lanes: idle lanes 48..63
  // would otherwise issue every broadcast ds_read, inflating the per-CU
  // LDS return traffic (the measured bottleneck) by 64/48.
  if (lane < KK) {
    float fA[8], fB[8];
#pragma unroll
    for (int k = 0; k < 8; ++k) fA[k] = fp[(size_t)k * KK];

    for (int t0 = 0; t0 < TT; t0 += 16) {
      // bulk prefetch rows t0+8..t0+15 into fB
#pragma unroll
      for (int k = 0; k < 8; ++k)
        fB[k] = fp[(size_t)((t0 + 8 + k) & (TT - 1)) * KK];
#pragma unroll
      for (int u = 0; u < 8; ++u) FSTEP(t0 + u, fA[u]);
      // bulk prefetch rows t0+16..t0+23 into fA
#pragma unroll
      for (int k = 0; k < 8; ++k)
        fA[k] = fp[(size_t)((t0 + 16 + k) & (TT - 1)) * KK];
#pragma unroll
      for (int u = 0; u < 8; ++u) FSTEP(t0 + 8 + u, fB[u]);
    }
  }

  // reconverged: lanes 48..63 alive again for the shuffle reduction
  float v = (lane < KK) ? (fv + tstop) : -FLT_MAX;
  int idx = lane;
#pragma unroll
  for (int off = 32; off >= 1; off >>= 1) {
    float ov = __shfl_xor(v, off);
    int oi = __shfl_xor(idx, off);
    bool take = (ov > v) || (ov == v && oi < idx);
    v = take ? ov : v;
    idx = take ? oi : idx;
  }
  if (lane == 0) { scores[b] = v; bestArr[b] = idx; }
}

__global__ __launch_bounds__(64, 1) void viterbi_bwd_mx(
    const float* __restrict__ feats, const float* __restrict__ trans,
    const float* __restrict__ mx, const int* __restrict__ bestArr,
    float* __restrict__ path) {
  __shared__ float tl[KK * KK];
  const int lane = threadIdx.x;
  const int b = blockIdx.x;
  const int rl = (lane < KK) ? lane : (KK - 1);
  for (int i = lane; i < KK * KK; i += 64) tl[i] = trans[i];
  __syncthreads();

  const float* fp = feats + (size_t)b * TT * KK + rl;
  const float* mp = mx + (size_t)b * TT * KK + rl;
  int tag = bestArr[b];  // wave-uniform

  float topA = mp[(size_t)(TT - 1) * KK];  // mx_{T-1}
  float MA[8], FE[8], MB[8], FB2[8];
  // block jb=T-1 needs mx/feat rows jb-1-u (u=0..7)
#pragma unroll
  for (int u = 0; u < 8; ++u) {
    MA[u] = mp[(size_t)(TT - 2 - u) * KK];
    FE[u] = fp[(size_t)(TT - 2 - u) * KK];
  }

  int myv = 0;  // lane (j&63) holds path[j]
  for (int jb = TT - 1; jb >= 15; jb -= 16) {
    // bulk load block jb-8 (rows jb-9-u), clamped
#pragma unroll
    for (int u = 0; u < 8; ++u) {
      int r = jb - 9 - u; int rc = r < 0 ? 0 : r;
      MB[u] = mp[(size_t)rc * KK];
      FB2[u] = fp[(size_t)rc * KK];
    }
    // process block jb with topA / MA / FE
#pragma unroll
    for (int u = 0; u < 8; ++u) {
      const int j = jb - u;
      if (lane == (j & 63)) myv = tag;
      if ((j & 63) == 0) path[(size_t)b * TT + j + lane] = (float)myv;
      float Tg = (u == 0) ? topA : MA[u - 1];
      float target = rdlane(Tg, tag);            // mx_j[tag]
      float s = (MA[u] + FE[u]) + tl[tag * KK + rl];
      unsigned long long bal = __ballot(s == target);  // lanes>=48 mirror 47
      tag = (int)__builtin_ctzll(bal);           // first p (np.argmax tie)
    }
    float topB = MA[7];  // mx_{jb-8}
    // bulk load block jb-16 (rows jb-17-u), clamped
#pragma unroll
    for (int u = 0; u < 8; ++u) {
      int r = jb - 17 - u; int rc = r < 0 ? 0 : r;
      MA[u] = mp[(size_t)rc * KK];
      FE[u] = fp[(size_t)rc * KK];
    }
    // process block jb-8 with topB / MB / FB2
#pragma unroll
    for (int u = 0; u < 8; ++u) {
      const int j = jb - 8 - u;
      if (lane == (j & 63)) myv = tag;
      if ((j & 63) == 0) path[(size_t)b * TT + j + lane] = (float)myv;
      float Tg = (u == 0) ? topB : MB[u - 1];
      float target = rdlane(Tg, tag);
      float s = (MB[u] + FB2[u]) + tl[tag * KK + rl];
      unsigned long long bal = __ballot(s == target);
      tag = (int)__builtin_ctzll(bal);  // garbage after j==0 vote: unused
    }
    topA = MB[7];
  }
}

// ---------------- fallback path (R1) ----------------

__global__ __launch_bounds__(64, 1) void viterbi_fwd_f(
    const float* __restrict__ feats, const float* __restrict__ trans,
    float* __restrict__ scores, unsigned char* __restrict__ bptr,
    int* __restrict__ bestArr) {
  __shared__ __align__(16) float fvbuf[64];
  const int lane = threadIdx.x;
  const int b = blockIdx.x;
  const int rl = (lane < KK) ? lane : (KK - 1);

  float tr[KK];
#pragma unroll
  for (int j = 0; j < 12; ++j) {
    float4 t4 = *(const float4*)(trans + rl * KK + 4 * j);
    tr[4 * j + 0] = t4.x; tr[4 * j + 1] = t4.y;
    tr[4 * j + 2] = t4.z; tr[4 * j + 3] = t4.w;
  }
  const float tstop = trans[(KK - 1) * KK + rl];

  if (lane < KK) fvbuf[lane] = (lane == 46) ? 0.0f : NEGV;
  __builtin_amdgcn_wave_barrier();

  const float* fp = feats + (size_t)b * TT * KK + rl;
  unsigned char* bp = bptr + (size_t)b * TT * KK + lane;

  float fbuf[4];
#pragma unroll
  for (int k = 0; k < 4; ++k) fbuf[k] = fp[(size_t)k * KK];

  float fv = NEGV;
  for (int t0 = 0; t0 < TT; t0 += 4) {
#pragma unroll
    for (int u = 0; u < 4; ++u) {
      const int t = t0 + u;
      float fvr[KK];
#pragma unroll
      for (int j = 0; j < 12; ++j) {
        float4 v4 = *(const float4*)(&fvbuf[4 * j]);
        fvr[4 * j + 0] = v4.x; fvr[4 * j + 1] = v4.y;
        fvr[4 * j + 2] = v4.z; fvr[4 * j + 3] = v4.w;
      }
      __builtin_amdgcn_wave_barrier();

      float bs0 = fvr[0] + tr[0], bs1 = fvr[12] + tr[12];
      float bs2 = fvr[24] + tr[24], bs3 = fvr[36] + tr[36];
      int bi0 = 0, bi1 = 12, bi2 = 24, bi3 = 36;
#pragma unroll
      for (int p = 1; p < 12; ++p) {
        float s0 = fvr[p] + tr[p];
        float s1 = fvr[12 + p] + tr[12 + p];
        float s2 = fvr[24 + p] + tr[24 + p];
        float s3 = fvr[36 + p] + tr[36 + p];
        if (s0 > bs0) { bs0 = s0; bi0 = p; }
        if (s1 > bs1) { bs1 = s1; bi1 = 12 + p; }
        if (s2 > bs2) { bs2 = s2; bi2 = 24 + p; }
        if (s3 > bs3) { bs3 = s3; bi3 = 36 + p; }
      }
      bool c1 = bs1 > bs0;
      float m01 = c1 ? bs1 : bs0; int i01 = c1 ? bi1 : bi0;
      bool c3 = bs3 > bs2;
      float m23 = c3 ? bs3 : bs2; int i23 = c3 ? bi3 : bi2;
      bool cf = m23 > m01;
      float m = cf ? m23 : m01; int bpi = cf ? i23 : i01;

      float nfv = m + fbuf[u];
      int tpre = t + 4; if (tpre >= TT) tpre = 0;
      fbuf[u] = fp[(size_t)tpre * KK];

      if (lane < KK) {
        bp[(size_t)t * KK] = (unsigned char)bpi;
        fvbuf[lane] = nfv;
        fv = nfv;
      }
      __builtin_amdgcn_wave_barrier();
    }
  }

  float v = (lane < KK) ? (fv + tstop) : -FLT_MAX;
  int idx = lane;
#pragma unroll
  for (int off = 32; off >= 1; off >>= 1) {
    float ov = __shfl_xor(v, off);
    int oi = __shfl_xor(idx, off);
    bool take = (ov > v) || (ov == v && oi < idx);
    v = take ? ov : v;
    idx = take ? oi : idx;
  }
  if (lane == 0) { scores[b] = v; bestArr[b] = idx; }
}

__global__ __launch_bounds__(256) void bwd_map(
    const unsigned char* __restrict__ bptr, unsigned char* __restrict__ cmap) {
  const int lane = threadIdx.x & 63;
  const int wg = blockIdx.x * 4 + (threadIdx.x >> 6);
  const int b = wg >> 4;
  const int c = wg & (CC - 1);
  const int rl = (lane < KK) ? lane : (KK - 1);
  const unsigned char* bp = bptr + ((size_t)b * TT + (size_t)c * LL) * KK + rl;

  int x = rl;
  const int CH = 16;
  int cur[CH], nxt[CH];
#pragma unroll
  for (int j = 0; j < CH; ++j) cur[j] = bp[(size_t)(LL - CH + j) * KK];
  for (int tb = LL - CH; tb >= 0; tb -= CH) {
    if (tb >= CH) {
#pragma unroll
      for (int j = 0; j < CH; ++j) nxt[j] = bp[(size_t)(tb - CH + j) * KK];
    }
#pragma unroll
    for (int j = CH - 1; j >= 0; --j) x = __shfl(cur[j], x);
    if (tb >= CH) {
#pragma unroll
      for (int j = 0; j < CH; ++j) cur[j] = nxt[j];
    }
  }
  if (lane < KK) cmap[(size_t)wg * KK + lane] = (unsigned char)x;
}

__global__ __launch_bounds__(256) void bwd_entry(
    const unsigned char* __restrict__ cmap, const int* __restrict__ bestArr,
    int* __restrict__ entry) {
  const int lane = threadIdx.x & 63;
  const int b = blockIdx.x * 4 + (threadIdx.x >> 6);
  const int rl = (lane < KK) ? lane : (KK - 1);

  int rows[CC];
#pragma unroll
  for (int c = 0; c < CC; ++c) rows[c] = cmap[((size_t)b * CC + c) * KK + rl];

  int tag = bestArr[b];
  int ev = 0;
#pragma unroll
  for (int c = CC - 1; c >= 0; --c) {
    if (lane == c) ev = tag;
    tag = __shfl(rows[c], tag);
  }
  if (lane < CC) entry[b * CC + lane] = ev;
}

__global__ __launch_bounds__(256) void bwd_emit(
    const unsigned char* __restrict__ bptr, const int* __restrict__ entry,
    float* __restrict__ path) {
  const int lane = threadIdx.x & 63;
  const int wg = blockIdx.x * 4 + (threadIdx.x >> 6);
  const int b = wg >> 4;
  const int c = wg & (CC - 1);
  const int rl = (lane < KK) ? lane : (KK - 1);
  const unsigned char* bp = bptr + ((size_t)b * TT + (size_t)c * LL) * KK + rl;

  int x = entry[b * CC + c];
  int myv = 0;
  const int CH = 16;
  int cur[CH], nxt[CH];
#pragma unroll
  for (int j = 0; j < CH; ++j) cur[j] = bp[(size_t)(LL - CH + j) * KK];
  for (int tb = LL - CH; tb >= 0; tb -= CH) {
    if (tb >= CH) {
#pragma unroll
      for (int j = 0; j < CH; ++j) nxt[j] = bp[(size_t)(tb - CH + j) * KK];
    }
#pragma unroll
    for (int j = CH - 1; j >= 0; --j) {
      if (lane == tb + j) myv = x;
      x = __shfl(cur[j], x);
    }
    if (tb >= CH) {
#pragma unroll
      for (int j = 0; j < CH; ++j) cur[j] = nxt[j];
    }
  }
  path[(size_t)b * TT + (size_t)c * LL + lane] = (float)myv;
}

extern "C" void kernel_launch(void* const* d_in, const int* in_sizes, int n_in,
                              void* d_out, int out_size, void* d_ws,
                              size_t ws_size, hipStream_t stream) {
  const float* feats = (const float*)d_in[0];
  const float* trans = (const float*)d_in[1];
  float* out = (float*)d_out;  // [0,1024): scores; then paths [B*T]

  const size_t MX_BYTES = (size_t)BB * TT * KK * sizeof(float);  // 201.3 MB
  if (ws_size >= MX_BYTES + 4096) {
    float* mx = (float*)d_ws;
    int* bestArr = (int*)((char*)d_ws + MX_BYTES);
    viterbi_fwd_mx<<<dim3(BB), dim3(64), 0, stream>>>(feats, trans, out, mx,
                                                      bestArr);
    viterbi_bwd_mx<<<dim3(BB), dim3(64), 0, stream>>>(feats, trans, mx,
                                                      bestArr, out + BB);
  } else {
    unsigned char* bptr = (unsigned char*)d_ws;
    char* p = (char*)d_ws + (size_t)BB * TT * KK;
    int* bestArr = (int*)p;
    p += BB * sizeof(int);
    unsigned char* cmap = (unsigned char*)p;
    p += (size_t)BB * CC * KK;
    int* entry = (int*)p;

    viterbi_fwd_f<<<dim3(BB), dim3(64), 0, stream>>>(feats, trans, out, bptr,
                                                     bestArr);
    bwd_map<<<dim3(BB * CC / 4), dim3(256), 0, stream>>>(bptr, cmap);
    bwd_entry<<<dim3(BB / 4), dim3(256), 0, stream>>>(cmap, bestArr, entry);
    bwd_emit<<<dim3(BB * CC / 4), dim3(256), 0, stream>>>(bptr, entry,
                                                          out + BB);
  }
}